// Round 2
// baseline (759.586 us; speedup 1.0000x reference)
//
#include <hip/hip_runtime.h>

typedef float v4f __attribute__((ext_vector_type(4)));

constexpr int PR  = 512;           // plane resolution
constexpr int CP  = 24;            // plane channels (OUT_DIM * RANK)
constexpr int FD  = 32;            // feature channels
constexpr int FR  = 128;           // feature resolution
constexpr int PSZ = PR * PR;
constexpr int NBUCK = 32768;       // 32^3 morton buckets

// ---------------------------------------------------------------------------
// Transpose 3 planes [24][512][512] -> ws [3][512][512][24] (channels innermost)
// ---------------------------------------------------------------------------
__global__ __launch_bounds__(256) void transpose_planes(
    const float* __restrict__ p0, const float* __restrict__ p1,
    const float* __restrict__ p2, float* __restrict__ wsT)
{
    __shared__ float lds[CP][256];
    int b   = blockIdx.x;
    int p   = b >> 10;             // 1024 blocks per plane
    int rem = b & 1023;
    int y   = rem >> 1;
    int x0  = (rem & 1) << 8;
    const float* src = (p == 0) ? p0 : (p == 1) ? p1 : p2;
    int t = threadIdx.x;
    #pragma unroll
    for (int c = 0; c < CP; ++c)
        lds[c][t] = src[c * PSZ + y * PR + x0 + t];
    __syncthreads();
    float* dst = wsT + ((size_t)((p * PR + y) * PR + x0)) * CP;
    #pragma unroll
    for (int k = 0; k < CP; ++k) {
        int idx = k * 256 + t;
        dst[idx] = lds[idx % CP][idx / CP];
    }
}

// ---------------------------------------------------------------------------
// Morton bucketing
// ---------------------------------------------------------------------------
__device__ inline int cell5(float p) {
    int c = (int)floorf((p + 1.0f) * 16.0f);
    return min(max(c, 0), 31);
}
__device__ inline unsigned spread3(unsigned v) {
    return (v & 1u) | ((v & 2u) << 2) | ((v & 4u) << 4) | ((v & 8u) << 6) | ((v & 16u) << 8);
}
__device__ inline unsigned morton_key(float x, float y, float z) {
    return spread3((unsigned)cell5(x)) | (spread3((unsigned)cell5(y)) << 1)
         | (spread3((unsigned)cell5(z)) << 2);
}

__global__ __launch_bounds__(256) void bucket_hist(
    const float* __restrict__ pts, unsigned* __restrict__ hist, int n)
{
    int i = blockIdx.x * blockDim.x + threadIdx.x;
    if (i >= n) return;
    float x = pts[3 * i], y = pts[3 * i + 1], z = pts[3 * i + 2];
    atomicAdd(&hist[morton_key(x, y, z)], 1u);
}

// single-block exclusive scan: hist[32768] -> cursor[32768]
__global__ __launch_bounds__(1024) void scan_offsets(
    const unsigned* __restrict__ hist, unsigned* __restrict__ cursor)
{
    __shared__ unsigned sums[1024];
    int t = threadIdx.x;
    const int base = t * (NBUCK / 1024);
    unsigned loc[NBUCK / 1024];
    unsigned s = 0;
    #pragma unroll
    for (int j = 0; j < NBUCK / 1024; ++j) { loc[j] = s; s += hist[base + j]; }
    sums[t] = s;
    __syncthreads();
    for (int off = 1; off < 1024; off <<= 1) {
        unsigned v = (t >= off) ? sums[t - off] : 0u;
        __syncthreads();
        sums[t] += v;
        __syncthreads();
    }
    unsigned blockbase = (t == 0) ? 0u : sums[t - 1];
    #pragma unroll
    for (int j = 0; j < NBUCK / 1024; ++j) cursor[base + j] = blockbase + loc[j];
}

__global__ __launch_bounds__(256) void scatter_pts(
    const float* __restrict__ pts, unsigned* __restrict__ cursor,
    v4f* __restrict__ sorted, int n)
{
    int i = blockIdx.x * blockDim.x + threadIdx.x;
    if (i >= n) return;
    float x = pts[3 * i], y = pts[3 * i + 1], z = pts[3 * i + 2];
    unsigned key = morton_key(x, y, z);
    unsigned pos = atomicAdd(&cursor[key], 1u);
    v4f v; v.x = x; v.y = y; v.z = z; v.w = __int_as_float(i);
    sorted[pos] = v;
}

// ---------------------------------------------------------------------------
// Per-point computation (planes from transposed layout)
// ---------------------------------------------------------------------------
__device__ inline void lrh_point(float px, float py, float pz,
                                 const float* __restrict__ wsT,
                                 const float* __restrict__ feat,
                                 float* __restrict__ outp)
{
    float cx[3] = {px, px, py};
    float cy[3] = {py, pz, pz};

    int   o00[3], o01[3], o10[3], o11[3];
    float w00[3], w01[3], w10[3], w11[3];
    #pragma unroll
    for (int p = 0; p < 3; ++p) {
        float ux = (cx[p] + 1.0f) * 0.5f * (float)(PR - 1);
        float uy = (cy[p] + 1.0f) * 0.5f * (float)(PR - 1);
        float lx = floorf(ux), ly = floorf(uy);
        float fx = ux - lx,   fy = uy - ly;
        int jx = (int)lx, jy = (int)ly;
        float vx0 = (jx   >= 0 && jx   < PR) ? 1.f : 0.f;
        float vx1 = (jx+1 >= 0 && jx+1 < PR) ? 1.f : 0.f;
        float vy0 = (jy   >= 0 && jy   < PR) ? 1.f : 0.f;
        float vy1 = (jy+1 >= 0 && jy+1 < PR) ? 1.f : 0.f;
        float wx0 = (1.f - fx) * vx0, wx1 = fx * vx1;
        float wy0 = (1.f - fy) * vy0, wy1 = fy * vy1;
        int ix0 = min(max(jx,     0), PR - 1);
        int ix1 = min(max(jx + 1, 0), PR - 1);
        int iy0 = min(max(jy,     0), PR - 1);
        int iy1 = min(max(jy + 1, 0), PR - 1);
        w00[p] = wx0 * wy0; w01[p] = wx1 * wy0;
        w10[p] = wx0 * wy1; w11[p] = wx1 * wy1;
        o00[p] = (iy0 * PR + ix0) * CP; o01[p] = (iy0 * PR + ix1) * CP;
        o10[p] = (iy1 * PR + ix0) * CP; o11[p] = (iy1 * PR + ix1) * CP;
    }

    const float* TB[3] = {wsT, wsT + (size_t)PSZ * CP, wsT + (size_t)2 * PSZ * CP};

    float interp[3] = {0.f, 0.f, 0.f};
    #pragma unroll
    for (int cg = 0; cg < 6; ++cg) {
        float pr[4] = {1.f, 1.f, 1.f, 1.f};
        #pragma unroll
        for (int p = 0; p < 3; ++p) {
            const v4f a = *(const v4f*)(TB[p] + o00[p] + cg * 4);
            const v4f b = *(const v4f*)(TB[p] + o01[p] + cg * 4);
            const v4f c = *(const v4f*)(TB[p] + o10[p] + cg * 4);
            const v4f d = *(const v4f*)(TB[p] + o11[p] + cg * 4);
            #pragma unroll
            for (int e = 0; e < 4; ++e) {
                float s = w00[p]*a[e] + w01[p]*b[e] + w10[p]*c[e] + w11[p]*d[e];
                pr[e] *= s;
            }
        }
        interp[cg >> 1] += (pr[0] + pr[1]) + (pr[2] + pr[3]);
    }

    int   offc[8];
    float wc[8];
    {
        float fr[3], v0[3], v1[3];
        int i0c[3], i1c[3];
        #pragma unroll
        for (int k = 0; k < 3; ++k) {
            float uu = (interp[k] + 1.0f) * 0.5f * (float)(FR - 1);
            float lf = floorf(uu);
            fr[k] = uu - lf;
            int jj = (int)lf;
            v0[k] = (jj   >= 0 && jj   < FR) ? 1.f : 0.f;
            v1[k] = (jj+1 >= 0 && jj+1 < FR) ? 1.f : 0.f;
            i0c[k] = min(max(jj,     0), FR - 1);
            i1c[k] = min(max(jj + 1, 0), FR - 1);
        }
        #pragma unroll
        for (int m = 0; m < 8; ++m) {
            int bx = m & 1, by = (m >> 1) & 1, bz = m >> 2;
            int xi = bx ? i1c[0] : i0c[0];
            int yi = by ? i1c[1] : i0c[1];
            int zi = bz ? i1c[2] : i0c[2];
            float wx = bx ? fr[0] * v1[0] : (1.f - fr[0]) * v0[0];
            float wy = by ? fr[1] * v1[1] : (1.f - fr[1]) * v0[1];
            float wz = bz ? fr[2] * v1[2] : (1.f - fr[2]) * v0[2];
            offc[m] = zi * FR * FR + yi * FR + xi;
            wc[m]   = wx * wy * wz;
        }
    }

    #pragma unroll
    for (int c4 = 0; c4 < FD / 4; ++c4) {
        v4f r;
        #pragma unroll
        for (int e = 0; e < 4; ++e) {
            const float* Fc = feat + (size_t)(c4 * 4 + e) * (FR * FR * FR);
            float v = 0.f;
            #pragma unroll
            for (int m = 0; m < 8; ++m) v = fmaf(wc[m], Fc[offc[m]], v);
            r[e] = v;
        }
        __builtin_nontemporal_store(r, (v4f*)(outp + c4 * 4));  // don't evict planes from L2
    }
}

__global__ __launch_bounds__(256) void lrh_sorted(
    const v4f* __restrict__ sorted,
    const float* __restrict__ wsT, const float* __restrict__ feat,
    float* __restrict__ out, int n)
{
    int i = blockIdx.x * blockDim.x + threadIdx.x;
    if (i >= n) return;
    v4f p = sorted[i];
    int orig = __float_as_int(p.w);
    lrh_point(p.x, p.y, p.z, wsT, feat, out + (size_t)orig * FD);
}

__global__ __launch_bounds__(256) void lrh_unsorted(
    const float* __restrict__ pts,
    const float* __restrict__ wsT, const float* __restrict__ feat,
    float* __restrict__ out, int n)
{
    int i = blockIdx.x * blockDim.x + threadIdx.x;
    if (i >= n) return;
    lrh_point(pts[3 * i], pts[3 * i + 1], pts[3 * i + 2], wsT, feat,
              out + (size_t)i * FD);
}

extern "C" void kernel_launch(void* const* d_in, const int* in_sizes, int n_in,
                              void* d_out, int out_size, void* d_ws, size_t ws_size,
                              hipStream_t stream) {
    const float* pts  = (const float*)d_in[0];
    const float* p0   = (const float*)d_in[1];
    const float* p1   = (const float*)d_in[2];
    const float* p2   = (const float*)d_in[3];
    const float* feat = (const float*)d_in[4];
    float* out = (float*)d_out;
    int n = in_sizes[0] / 3;

    const size_t off_trans  = 0;
    const size_t sz_trans   = (size_t)3 * PSZ * CP * sizeof(float);     // 75.5 MB
    const size_t off_sorted = sz_trans;
    const size_t sz_sorted  = (size_t)n * sizeof(v4f);                  // 16 MB
    const size_t off_hist   = off_sorted + sz_sorted;
    const size_t off_cursor = off_hist + NBUCK * sizeof(unsigned);
    const size_t need_sort  = off_cursor + NBUCK * sizeof(unsigned);

    int blocks = (n + 255) / 256;
    char* ws = (char*)d_ws;

    if (d_ws && ws_size >= need_sort) {
        float*    wsT    = (float*)(ws + off_trans);
        v4f*      sorted = (v4f*)(ws + off_sorted);
        unsigned* hist   = (unsigned*)(ws + off_hist);
        unsigned* cursor = (unsigned*)(ws + off_cursor);

        transpose_planes<<<3 * 1024, 256, 0, stream>>>(p0, p1, p2, wsT);
        hipMemsetAsync(hist, 0, NBUCK * sizeof(unsigned), stream);
        bucket_hist<<<blocks, 256, 0, stream>>>(pts, hist, n);
        scan_offsets<<<1, 1024, 0, stream>>>(hist, cursor);
        scatter_pts<<<blocks, 256, 0, stream>>>(pts, cursor, sorted, n);
        lrh_sorted<<<blocks, 256, 0, stream>>>(sorted, wsT, feat, out, n);
    } else if (d_ws && ws_size >= sz_trans) {
        float* wsT = (float*)(ws + off_trans);
        transpose_planes<<<3 * 1024, 256, 0, stream>>>(p0, p1, p2, wsT);
        lrh_unsorted<<<blocks, 256, 0, stream>>>(pts, wsT, feat, out, n);
    }
    // (ws is always provided at >=92MB for this problem; no tiny-ws fallback)
}

// Round 3
// 710.497 us; speedup vs baseline: 1.0691x; 1.0691x over previous
//
#include <hip/hip_runtime.h>

typedef float v4f __attribute__((ext_vector_type(4)));

constexpr int PR  = 512;           // plane resolution
constexpr int CP  = 24;            // plane channels (OUT_DIM * RANK)
constexpr int FD  = 32;            // feature channels
constexpr int FR  = 128;           // feature resolution
constexpr int PSZ = PR * PR;
constexpr int NBUCK = 32768;       // 32^3 morton buckets

// ---------------------------------------------------------------------------
// Transpose 3 planes [24][512][512] -> ws [3][512][512][24] (channels innermost)
// ---------------------------------------------------------------------------
__global__ __launch_bounds__(256) void transpose_planes(
    const float* __restrict__ p0, const float* __restrict__ p1,
    const float* __restrict__ p2, float* __restrict__ wsT)
{
    __shared__ float lds[CP][256];
    int b   = blockIdx.x;
    int p   = b >> 10;             // 1024 blocks per plane
    int rem = b & 1023;
    int y   = rem >> 1;
    int x0  = (rem & 1) << 8;
    const float* src = (p == 0) ? p0 : (p == 1) ? p1 : p2;
    int t = threadIdx.x;
    #pragma unroll
    for (int c = 0; c < CP; ++c)
        lds[c][t] = src[c * PSZ + y * PR + x0 + t];
    __syncthreads();
    float* dst = wsT + ((size_t)((p * PR + y) * PR + x0)) * CP;
    #pragma unroll
    for (int k = 0; k < CP; ++k) {
        int idx = k * 256 + t;
        dst[idx] = lds[idx % CP][idx / CP];
    }
}

// ---------------------------------------------------------------------------
// Morton bucketing
// ---------------------------------------------------------------------------
__device__ inline int cell5(float p) {
    int c = (int)floorf((p + 1.0f) * 16.0f);
    return min(max(c, 0), 31);
}
__device__ inline unsigned spread3(unsigned v) {
    return (v & 1u) | ((v & 2u) << 2) | ((v & 4u) << 4) | ((v & 8u) << 6) | ((v & 16u) << 8);
}
__device__ inline unsigned morton_key(float x, float y, float z) {
    return spread3((unsigned)cell5(x)) | (spread3((unsigned)cell5(y)) << 1)
         | (spread3((unsigned)cell5(z)) << 2);
}

__global__ __launch_bounds__(256) void bucket_hist(
    const float* __restrict__ pts, unsigned* __restrict__ hist, int n)
{
    int i = blockIdx.x * blockDim.x + threadIdx.x;
    if (i >= n) return;
    float x = pts[3 * i], y = pts[3 * i + 1], z = pts[3 * i + 2];
    atomicAdd(&hist[morton_key(x, y, z)], 1u);
}

// single-block exclusive scan: hist[32768] -> cursor[32768]
__global__ __launch_bounds__(1024) void scan_offsets(
    const unsigned* __restrict__ hist, unsigned* __restrict__ cursor)
{
    __shared__ unsigned sums[1024];
    int t = threadIdx.x;
    const int base = t * (NBUCK / 1024);
    unsigned loc[NBUCK / 1024];
    unsigned s = 0;
    #pragma unroll
    for (int j = 0; j < NBUCK / 1024; ++j) { loc[j] = s; s += hist[base + j]; }
    sums[t] = s;
    __syncthreads();
    for (int off = 1; off < 1024; off <<= 1) {
        unsigned v = (t >= off) ? sums[t - off] : 0u;
        __syncthreads();
        sums[t] += v;
        __syncthreads();
    }
    unsigned blockbase = (t == 0) ? 0u : sums[t - 1];
    #pragma unroll
    for (int j = 0; j < NBUCK / 1024; ++j) cursor[base + j] = blockbase + loc[j];
}

__global__ __launch_bounds__(256) void scatter_pts(
    const float* __restrict__ pts, unsigned* __restrict__ cursor,
    v4f* __restrict__ sorted, int n)
{
    int i = blockIdx.x * blockDim.x + threadIdx.x;
    if (i >= n) return;
    float x = pts[3 * i], y = pts[3 * i + 1], z = pts[3 * i + 2];
    unsigned key = morton_key(x, y, z);
    unsigned pos = atomicAdd(&cursor[key], 1u);
    v4f v; v.x = x; v.y = y; v.z = z; v.w = __int_as_float(i);
    sorted[pos] = v;
}

// ---------------------------------------------------------------------------
// Per-point computation (planes from transposed layout).
// pts are in [-1,1] so plane corner validity masks are unnecessary:
// clamp-only is mathematically identical (boundary corner has weight 0).
// ---------------------------------------------------------------------------
__device__ inline void lrh_point(float px, float py, float pz,
                                 const float* __restrict__ wsT,
                                 const float* __restrict__ feat,
                                 float* __restrict__ outp)
{
    float cx[3] = {px, px, py};
    float cy[3] = {py, pz, pz};

    int   o00[3], o01[3], o10[3], o11[3];
    float w00[3], w01[3], w10[3], w11[3];
    #pragma unroll
    for (int p = 0; p < 3; ++p) {
        float ux = (cx[p] + 1.0f) * 0.5f * (float)(PR - 1);
        float uy = (cy[p] + 1.0f) * 0.5f * (float)(PR - 1);
        float lx = floorf(ux), ly = floorf(uy);
        float fx = ux - lx,   fy = uy - ly;
        int jx = (int)lx, jy = (int)ly;
        int ix0 = min(max(jx,     0), PR - 1);
        int ix1 = min(jx + 1, PR - 1);
        int iy0 = min(max(jy,     0), PR - 1);
        int iy1 = min(jy + 1, PR - 1);
        float wx0 = 1.f - fx, wx1 = fx;
        float wy0 = 1.f - fy, wy1 = fy;
        w00[p] = wx0 * wy0; w01[p] = wx1 * wy0;
        w10[p] = wx0 * wy1; w11[p] = wx1 * wy1;
        o00[p] = (iy0 * PR + ix0) * CP; o01[p] = (iy0 * PR + ix1) * CP;
        o10[p] = (iy1 * PR + ix0) * CP; o11[p] = (iy1 * PR + ix1) * CP;
    }

    const float* TB[3] = {wsT, wsT + (size_t)PSZ * CP, wsT + (size_t)2 * PSZ * CP};

    float interp[3] = {0.f, 0.f, 0.f};
    #pragma unroll
    for (int cg = 0; cg < 6; ++cg) {
        float pr[4] = {1.f, 1.f, 1.f, 1.f};
        #pragma unroll
        for (int p = 0; p < 3; ++p) {
            const v4f a = *(const v4f*)(TB[p] + o00[p] + cg * 4);
            const v4f b = *(const v4f*)(TB[p] + o01[p] + cg * 4);
            const v4f c = *(const v4f*)(TB[p] + o10[p] + cg * 4);
            const v4f d = *(const v4f*)(TB[p] + o11[p] + cg * 4);
            #pragma unroll
            for (int e = 0; e < 4; ++e) {
                float s = w00[p]*a[e] + w01[p]*b[e] + w10[p]*c[e] + w11[p]*d[e];
                pr[e] *= s;
            }
        }
        interp[cg >> 1] += (pr[0] + pr[1]) + (pr[2] + pr[3]);
    }

    // trilinear feature lookup (interp may fall outside [-1,1]; keep masks)
    int   offc[8];
    float wc[8];
    {
        float fr[3], v0[3], v1[3];
        int i0c[3], i1c[3];
        #pragma unroll
        for (int k = 0; k < 3; ++k) {
            float uu = (interp[k] + 1.0f) * 0.5f * (float)(FR - 1);
            float lf = floorf(uu);
            fr[k] = uu - lf;
            int jj = (int)lf;
            v0[k] = (jj   >= 0 && jj   < FR) ? 1.f : 0.f;
            v1[k] = (jj+1 >= 0 && jj+1 < FR) ? 1.f : 0.f;
            i0c[k] = min(max(jj,     0), FR - 1);
            i1c[k] = min(max(jj + 1, 0), FR - 1);
        }
        #pragma unroll
        for (int m = 0; m < 8; ++m) {
            int bx = m & 1, by = (m >> 1) & 1, bz = m >> 2;
            int xi = bx ? i1c[0] : i0c[0];
            int yi = by ? i1c[1] : i0c[1];
            int zi = bz ? i1c[2] : i0c[2];
            float wx = bx ? fr[0] * v1[0] : (1.f - fr[0]) * v0[0];
            float wy = by ? fr[1] * v1[1] : (1.f - fr[1]) * v0[1];
            float wz = bz ? fr[2] * v1[2] : (1.f - fr[2]) * v0[2];
            offc[m] = zi * FR * FR + yi * FR + xi;
            wc[m]   = wx * wy * wz;
        }
    }

    #pragma unroll
    for (int c4 = 0; c4 < FD / 4; ++c4) {
        v4f r;
        #pragma unroll
        for (int e = 0; e < 4; ++e) {
            const float* Fc = feat + (size_t)(c4 * 4 + e) * (FR * FR * FR);
            float v = 0.f;
            #pragma unroll
            for (int m = 0; m < 8; ++m) v = fmaf(wc[m], Fc[offc[m]], v);
            r[e] = v;
        }
        *(v4f*)(outp + c4 * 4) = r;   // plain store: lines merge in L2, no RMW
    }
}

// XCD-chunked swizzle (bijective, m204 form): each XCD gets a contiguous
// run of the sorted-point order so its private L2 keeps the plane window.
__global__ __launch_bounds__(256, 4) void lrh_sorted(
    const v4f* __restrict__ sorted,
    const float* __restrict__ wsT, const float* __restrict__ feat,
    float* __restrict__ out, int n)
{
    int nwg = gridDim.x;
    int q = nwg >> 3, r = nwg & 7;
    int xcd = blockIdx.x & 7, j = blockIdx.x >> 3;
    int wg = (xcd < r ? xcd * (q + 1) : r * (q + 1) + (xcd - r) * q) + j;
    int i = wg * 256 + threadIdx.x;
    if (i >= n) return;
    v4f p = sorted[i];
    int orig = __float_as_int(p.w);
    lrh_point(p.x, p.y, p.z, wsT, feat, out + (size_t)orig * FD);
}

extern "C" void kernel_launch(void* const* d_in, const int* in_sizes, int n_in,
                              void* d_out, int out_size, void* d_ws, size_t ws_size,
                              hipStream_t stream) {
    const float* pts  = (const float*)d_in[0];
    const float* p0   = (const float*)d_in[1];
    const float* p1   = (const float*)d_in[2];
    const float* p2   = (const float*)d_in[3];
    const float* feat = (const float*)d_in[4];
    float* out = (float*)d_out;
    int n = in_sizes[0] / 3;

    const size_t off_trans  = 0;
    const size_t sz_trans   = (size_t)3 * PSZ * CP * sizeof(float);     // 75.5 MB
    const size_t off_sorted = sz_trans;
    const size_t sz_sorted  = (size_t)n * sizeof(v4f);                  // 16 MB
    const size_t off_hist   = off_sorted + sz_sorted;
    const size_t off_cursor = off_hist + NBUCK * sizeof(unsigned);

    int blocks = (n + 255) / 256;
    char* ws = (char*)d_ws;

    float*    wsT    = (float*)(ws + off_trans);
    v4f*      sorted = (v4f*)(ws + off_sorted);
    unsigned* hist   = (unsigned*)(ws + off_hist);
    unsigned* cursor = (unsigned*)(ws + off_cursor);

    transpose_planes<<<3 * 1024, 256, 0, stream>>>(p0, p1, p2, wsT);
    hipMemsetAsync(hist, 0, NBUCK * sizeof(unsigned), stream);
    bucket_hist<<<blocks, 256, 0, stream>>>(pts, hist, n);
    scan_offsets<<<1, 1024, 0, stream>>>(hist, cursor);
    scatter_pts<<<blocks, 256, 0, stream>>>(pts, cursor, sorted, n);
    lrh_sorted<<<blocks, 256, 0, stream>>>(sorted, wsT, feat, out, n);
}